// Round 1
// baseline (334.179 us; speedup 1.0000x reference)
//
#include <hip/hip_runtime.h>
#include <math.h>

// Problem constants (fixed by setup_inputs)
namespace {
constexpr int B_  = 8;
constexpr int U_  = 16384;   // off-grid tokens per batch
constexpr int G_  = 64;
constexpr int S_  = 4096;    // G*G grid cells
constexpr int E_  = 128;     // embedding dim
constexpr int H_  = 8;       // heads
constexpr int DH_ = 16;      // head dim
constexpr int TM_ = 16;      // tokens per block
}

// ------------------------------------------------------------------
// K0: Q[s][e] = (latents[s] @ Wq)[e] * (1/sqrt(DH))   -- batch-independent
// ------------------------------------------------------------------
__global__ __launch_bounds__(128) void qproj_kernel(
    const float* __restrict__ latents, const float* __restrict__ Wq,
    float* __restrict__ Q) {
  const int j  = threadIdx.x;            // output dim 0..127
  const int t0 = blockIdx.x * TM_;       // cell base
  __shared__ float zs[TM_ * E_];

  const float4* src4 = (const float4*)(latents + (size_t)t0 * E_);
  float4* zs4 = (float4*)zs;
#pragma unroll
  for (int i = 0; i < (TM_ * E_ / 4) / 128; ++i) zs4[i * 128 + j] = src4[i * 128 + j];
  __syncthreads();

  float acc[TM_];
#pragma unroll
  for (int t = 0; t < TM_; ++t) acc[t] = 0.0f;

  for (int e = 0; e < E_; e += 4) {
    const float w0 = Wq[(e + 0) * E_ + j];
    const float w1 = Wq[(e + 1) * E_ + j];
    const float w2 = Wq[(e + 2) * E_ + j];
    const float w3 = Wq[(e + 3) * E_ + j];
#pragma unroll
    for (int t = 0; t < TM_; ++t) {
      const float4 z4 = *(const float4*)&zs[t * E_ + e];
      acc[t] = fmaf(z4.x, w0, fmaf(z4.y, w1, fmaf(z4.z, w2, fmaf(z4.w, w3, acc[t]))));
    }
  }
#pragma unroll
  for (int t = 0; t < TM_; ++t) Q[(size_t)(t0 + t) * E_ + j] = acc[t] * 0.25f;
}

// ------------------------------------------------------------------
// K1: on-grid token init. For every cell tok=b*S+s:
//   k = z@Wk, v = z@Wv, w_h = exp(q_h . k_h)
//   denom[tok,h] = w_h ;  num[tok,e] = w_{e/16} * v_e   (num lives in d_out)
// Fully initializes num/denom (no memset needed).
// ------------------------------------------------------------------
__global__ __launch_bounds__(128) void ongrid_kernel(
    const float* __restrict__ zc_on, const float* __restrict__ fake,
    const int* __restrict__ ignore_flag,
    const float* __restrict__ Wk, const float* __restrict__ Wv,
    const float* __restrict__ Q,
    float* __restrict__ num, float* __restrict__ denom) {
  const int j  = threadIdx.x;
  const int t0 = blockIdx.x * TM_;       // token (=cell) base
  __shared__ float zs[TM_ * E_];
  __shared__ float ks[TM_ * E_];
  __shared__ float w_s[TM_ * H_];

  const int ign = *ignore_flag;
  if (!ign) {
    const float4* src4 = (const float4*)(zc_on + (size_t)t0 * E_);
    float4* zs4 = (float4*)zs;
#pragma unroll
    for (int i = 0; i < 4; ++i) zs4[i * 128 + j] = src4[i * 128 + j];
  } else {
    const float f = fake[j];
#pragma unroll
    for (int t = 0; t < TM_; ++t) zs[t * E_ + j] = f;
  }
  __syncthreads();

  float acck[TM_], accv[TM_];
#pragma unroll
  for (int t = 0; t < TM_; ++t) { acck[t] = 0.0f; accv[t] = 0.0f; }

  for (int e = 0; e < E_; e += 4) {
    const float k0 = Wk[(e + 0) * E_ + j], v0 = Wv[(e + 0) * E_ + j];
    const float k1 = Wk[(e + 1) * E_ + j], v1 = Wv[(e + 1) * E_ + j];
    const float k2 = Wk[(e + 2) * E_ + j], v2 = Wv[(e + 2) * E_ + j];
    const float k3 = Wk[(e + 3) * E_ + j], v3 = Wv[(e + 3) * E_ + j];
#pragma unroll
    for (int t = 0; t < TM_; ++t) {
      const float4 z4 = *(const float4*)&zs[t * E_ + e];
      acck[t] = fmaf(z4.x, k0, fmaf(z4.y, k1, fmaf(z4.z, k2, fmaf(z4.w, k3, acck[t]))));
      accv[t] = fmaf(z4.x, v0, fmaf(z4.y, v1, fmaf(z4.z, v2, fmaf(z4.w, v3, accv[t]))));
    }
  }
#pragma unroll
  for (int t = 0; t < TM_; ++t) ks[t * E_ + j] = acck[t];
  __syncthreads();

  {  // scores: thread j -> (t = j>>3, h = j&7)
    const int t = j >> 3, h = j & 7;
    const int tok = t0 + t;
    const int s = tok & (S_ - 1);
    const float* qrow = Q + (size_t)s * E_ + h * DH_;
    const float* krow = ks + t * E_ + h * DH_;
    float sc = 0.0f;
#pragma unroll
    for (int d = 0; d < DH_; ++d) sc = fmaf(qrow[d], krow[d], sc);
    const float w = expf(sc);
    w_s[t * H_ + h] = w;
    denom[(size_t)tok * H_ + h] = w;
  }
  __syncthreads();

#pragma unroll
  for (int t = 0; t < TM_; ++t)
    num[(size_t)(t0 + t) * E_ + j] = w_s[t * H_ + (j >> 4)] * accv[t];
}

// ------------------------------------------------------------------
// K2: off-grid scatter. For each off-grid token: bucketize, k/v project,
// w_h = exp(q_h . k_h), atomically accumulate into num/denom.
// ------------------------------------------------------------------
__global__ __launch_bounds__(128) void offgrid_kernel(
    const float* __restrict__ xc_off, const float* __restrict__ zc_off,
    const float* __restrict__ Wk, const float* __restrict__ Wv,
    const float* __restrict__ Q,
    float* __restrict__ num, float* __restrict__ denom) {
  const int j  = threadIdx.x;
  const int t0 = blockIdx.x * TM_;       // token base, token = b*U + u
  __shared__ float zs[TM_ * E_];
  __shared__ float ks[TM_ * E_];
  __shared__ float w_s[TM_ * H_];
  __shared__ int   segs[TM_];

  {
    const float4* src4 = (const float4*)(zc_off + (size_t)t0 * E_);
    float4* zs4 = (float4*)zs;
#pragma unroll
    for (int i = 0; i < 4; ++i) zs4[i * 128 + j] = src4[i * 128 + j];
  }
  if (j < TM_) {
    const int tok = t0 + j;
    const int b = tok >> 14;  // / U_
    // EXACT replication of reference fp32 bucketize: xmin=0, xmax=1, sp=1/63
    const float sp = 1.0f / 63.0f;
    const float half = sp * 0.5f;
    const float x0 = xc_off[(size_t)tok * 2 + 0];
    const float x1 = xc_off[(size_t)tok * 2 + 1];
    float n0 = floorf((x0 - 0.0f + half) / sp);
    float n1 = floorf((x1 - 0.0f + half) / sp);
    n0 = fminf(fmaxf(n0, 0.0f), 63.0f);
    n1 = fminf(fmaxf(n1, 0.0f), 63.0f);
    const int idx = (int)(n0 * 64.0f + n1);
    segs[j] = b * S_ + idx;
  }
  __syncthreads();

  float acck[TM_], accv[TM_];
#pragma unroll
  for (int t = 0; t < TM_; ++t) { acck[t] = 0.0f; accv[t] = 0.0f; }

  for (int e = 0; e < E_; e += 4) {
    const float k0 = Wk[(e + 0) * E_ + j], v0 = Wv[(e + 0) * E_ + j];
    const float k1 = Wk[(e + 1) * E_ + j], v1 = Wv[(e + 1) * E_ + j];
    const float k2 = Wk[(e + 2) * E_ + j], v2 = Wv[(e + 2) * E_ + j];
    const float k3 = Wk[(e + 3) * E_ + j], v3 = Wv[(e + 3) * E_ + j];
#pragma unroll
    for (int t = 0; t < TM_; ++t) {
      const float4 z4 = *(const float4*)&zs[t * E_ + e];
      acck[t] = fmaf(z4.x, k0, fmaf(z4.y, k1, fmaf(z4.z, k2, fmaf(z4.w, k3, acck[t]))));
      accv[t] = fmaf(z4.x, v0, fmaf(z4.y, v1, fmaf(z4.z, v2, fmaf(z4.w, v3, accv[t]))));
    }
  }
#pragma unroll
  for (int t = 0; t < TM_; ++t) ks[t * E_ + j] = acck[t];
  __syncthreads();

  {
    const int t = j >> 3, h = j & 7;
    const int seg = segs[t];
    const int s = seg & (S_ - 1);
    const float* qrow = Q + (size_t)s * E_ + h * DH_;
    const float* krow = ks + t * E_ + h * DH_;
    float sc = 0.0f;
#pragma unroll
    for (int d = 0; d < DH_; ++d) sc = fmaf(qrow[d], krow[d], sc);
    const float w = expf(sc);
    w_s[t * H_ + h] = w;
    atomicAdd(&denom[(size_t)seg * H_ + h], w);
  }
  __syncthreads();

#pragma unroll
  for (int t = 0; t < TM_; ++t)
    atomicAdd(&num[(size_t)segs[t] * E_ + j], w_s[t * H_ + (j >> 4)] * accv[t]);
}

// ------------------------------------------------------------------
// K3: finalize in-place: out = (num/denom) @ Wo
// ------------------------------------------------------------------
__global__ __launch_bounds__(128) void finalize_kernel(
    const float* __restrict__ Wo, const float* __restrict__ denom,
    float* __restrict__ out) {
  const int j  = threadIdx.x;
  const int t0 = blockIdx.x * TM_;
  __shared__ float as[TM_ * E_];

#pragma unroll
  for (int t = 0; t < TM_; ++t) {
    const float d = denom[(size_t)(t0 + t) * H_ + (j >> 4)];
    as[t * E_ + j] = out[(size_t)(t0 + t) * E_ + j] / d;
  }
  __syncthreads();

  float acc[TM_];
#pragma unroll
  for (int t = 0; t < TM_; ++t) acc[t] = 0.0f;

  for (int e = 0; e < E_; e += 4) {
    const float w0 = Wo[(e + 0) * E_ + j];
    const float w1 = Wo[(e + 1) * E_ + j];
    const float w2 = Wo[(e + 2) * E_ + j];
    const float w3 = Wo[(e + 3) * E_ + j];
#pragma unroll
    for (int t = 0; t < TM_; ++t) {
      const float4 a4 = *(const float4*)&as[t * E_ + e];
      acc[t] = fmaf(a4.x, w0, fmaf(a4.y, w1, fmaf(a4.z, w2, fmaf(a4.w, w3, acc[t]))));
    }
  }
#pragma unroll
  for (int t = 0; t < TM_; ++t) out[(size_t)(t0 + t) * E_ + j] = acc[t];
}

// ------------------------------------------------------------------
extern "C" void kernel_launch(void* const* d_in, const int* in_sizes, int n_in,
                              void* d_out, int out_size, void* d_ws, size_t ws_size,
                              hipStream_t stream) {
  const float* xc_off  = (const float*)d_in[0];
  // d_in[1] = xc_on_grid (unused: xmin/xmax/spacing are analytically exact)
  const float* zc_off  = (const float*)d_in[2];
  const float* zc_on   = (const float*)d_in[3];
  const float* latents = (const float*)d_in[4];
  const float* fake    = (const float*)d_in[5];
  const float* Wq      = (const float*)d_in[6];
  const float* Wk      = (const float*)d_in[7];
  const float* Wv      = (const float*)d_in[8];
  const float* Wo      = (const float*)d_in[9];
  const int*   ignore  = (const int*)d_in[10];

  float* out   = (float*)d_out;                 // doubles as num accumulator
  float* Q     = (float*)d_ws;                  // S*E floats = 2 MB
  float* denom = Q + (size_t)S_ * E_;           // B*S*H floats = 1 MB

  qproj_kernel<<<S_ / TM_, 128, 0, stream>>>(latents, Wq, Q);
  ongrid_kernel<<<(B_ * S_) / TM_, 128, 0, stream>>>(zc_on, fake, ignore, Wk, Wv, Q, out, denom);
  offgrid_kernel<<<(B_ * U_) / TM_, 128, 0, stream>>>(xc_off, zc_off, Wk, Wv, Q, out, denom);
  finalize_kernel<<<(B_ * S_) / TM_, 128, 0, stream>>>(Wo, denom, out);
}

// Round 2
// 216.268 us; speedup vs baseline: 1.5452x; 1.5452x over previous
//
#include <hip/hip_runtime.h>
#include <math.h>

namespace {
constexpr int B_  = 8;
constexpr int U_  = 16384;
constexpr int S_  = 4096;
constexpr int E_  = 128;
constexpr int H_  = 8;
}

typedef __attribute__((ext_vector_type(8))) short bf16x8;
typedef __attribute__((ext_vector_type(4))) float f32x4;

__device__ inline unsigned short bf16rne(float x) {
  unsigned u = __float_as_uint(x);
  u = u + 0x7fffu + ((u >> 16) & 1u);
  return (unsigned short)(u >> 16);
}

__device__ inline bf16x8 pack8(float4 a, float4 b) {
  bf16x8 r;
  r[0] = (short)bf16rne(a.x); r[1] = (short)bf16rne(a.y);
  r[2] = (short)bf16rne(a.z); r[3] = (short)bf16rne(a.w);
  r[4] = (short)bf16rne(b.x); r[5] = (short)bf16rne(b.y);
  r[6] = (short)bf16rne(b.z); r[7] = (short)bf16rne(b.w);
  return r;
}

// ------------------------------------------------------------------
// P0: swizzle all four weight matrices fp32 -> bf16 B-fragment layout.
// dst[w][ ((k>>3)*128 + n)*8 + (k&7) ] = bf16(W[k*128+n])
// ------------------------------------------------------------------
__global__ __launch_bounds__(256) void prep_weights(
    const float* __restrict__ Wq, const float* __restrict__ Wk,
    const float* __restrict__ Wv, const float* __restrict__ Wo,
    unsigned short* __restrict__ dst) {
  const int i = blockIdx.x * 256 + threadIdx.x;   // 0..65535
  const int w = i >> 14, e = i & 16383;
  const int k = e >> 7, n = e & 127;
  const float* src = (w == 0) ? Wq : (w == 1) ? Wk : (w == 2) ? Wv : Wo;
  dst[w * 16384 + (((k >> 3) * 128 + n) << 3) + (k & 7)] = bf16rne(src[e]);
}

// ------------------------------------------------------------------
// K0: Q = 0.25 * latents @ Wq   (fp32 out, [S, E])
// ------------------------------------------------------------------
__global__ __launch_bounds__(256, 4) void qproj_mfma(
    const float* __restrict__ latents, const unsigned short* __restrict__ Wq_sw,
    float* __restrict__ Q) {
  __shared__ __align__(16) unsigned short wq[16384];
  const int tid = threadIdx.x;
  {
    const uint4* s = (const uint4*)Wq_sw;
    uint4* d = (uint4*)wq;
#pragma unroll
    for (int i = 0; i < 8; ++i) d[i * 256 + tid] = s[i * 256 + tid];
  }
  __syncthreads();

  const int wave = tid >> 6, lane = tid & 63;
  const int c = lane & 15, g = lane >> 4;
  const int t0w = blockIdx.x * 64 + wave * 16;

  f32x4 acc[8];
#pragma unroll
  for (int i = 0; i < 8; ++i) acc[i] = {0.f, 0.f, 0.f, 0.f};

  const float* arow = latents + (size_t)(t0w + c) * E_ + g * 8;
  const bf16x8* bq = (const bf16x8*)wq;
#pragma unroll
  for (int ks = 0; ks < 4; ++ks) {
    float4 a0 = *(const float4*)(arow + ks * 32);
    float4 a1 = *(const float4*)(arow + ks * 32 + 4);
    bf16x8 af = pack8(a0, a1);
    const int bo = (ks * 4 + g) * 128 + c;
#pragma unroll
    for (int nt = 0; nt < 8; ++nt)
      acc[nt] = __builtin_amdgcn_mfma_f32_16x16x32_bf16(af, bq[bo + nt * 16], acc[nt], 0, 0, 0);
  }
#pragma unroll
  for (int nt = 0; nt < 8; ++nt)
#pragma unroll
    for (int r = 0; r < 4; ++r)
      Q[(size_t)(t0w + g * 4 + r) * E_ + nt * 16 + c] = acc[nt][r] * 0.25f;
}

// ------------------------------------------------------------------
// K1: on-grid init.  K=z@Wk, V=z@Wv, w=exp(q.k);
// denom[tok][h]=w ; num[tok][n]=w*V  (direct stores, initializes both)
// ------------------------------------------------------------------
__global__ __launch_bounds__(256, 2) void ongrid_mfma(
    const float* __restrict__ zc_on, const float* __restrict__ fake,
    const int* __restrict__ ignore_flag,
    const unsigned short* __restrict__ Wk_sw, const unsigned short* __restrict__ Wv_sw,
    const float* __restrict__ Q,
    float* __restrict__ num, float* __restrict__ denom) {
  __shared__ __align__(16) unsigned short wk[16384];
  __shared__ __align__(16) unsigned short wv[16384];
  const int tid = threadIdx.x;
  {
    const uint4* sk = (const uint4*)Wk_sw;
    const uint4* sv = (const uint4*)Wv_sw;
    uint4* dk = (uint4*)wk; uint4* dv = (uint4*)wv;
#pragma unroll
    for (int i = 0; i < 8; ++i) {
      dk[i * 256 + tid] = sk[i * 256 + tid];
      dv[i * 256 + tid] = sv[i * 256 + tid];
    }
  }
  const int ign = *ignore_flag;
  __syncthreads();

  const int wave = tid >> 6, lane = tid & 63;
  const int c = lane & 15, g = lane >> 4;
  const int t0w = blockIdx.x * 64 + wave * 16;   // token = b*S + s

  f32x4 accK[8], accV[8];
#pragma unroll
  for (int i = 0; i < 8; ++i) { accK[i] = {0.f,0.f,0.f,0.f}; accV[i] = {0.f,0.f,0.f,0.f}; }

  const float* arow = ign ? (fake + g * 8)
                          : (zc_on + (size_t)(t0w + c) * E_ + g * 8);
  const bf16x8* bk = (const bf16x8*)wk;
  const bf16x8* bv = (const bf16x8*)wv;
#pragma unroll
  for (int ks = 0; ks < 4; ++ks) {
    float4 a0 = *(const float4*)(arow + ks * 32);
    float4 a1 = *(const float4*)(arow + ks * 32 + 4);
    bf16x8 af = pack8(a0, a1);
    const int bo = (ks * 4 + g) * 128 + c;
#pragma unroll
    for (int nt = 0; nt < 8; ++nt) {
      accK[nt] = __builtin_amdgcn_mfma_f32_16x16x32_bf16(af, bk[bo + nt * 16], accK[nt], 0, 0, 0);
      accV[nt] = __builtin_amdgcn_mfma_f32_16x16x32_bf16(af, bv[bo + nt * 16], accV[nt], 0, 0, 0);
    }
  }

  float w_arr[8][4];
#pragma unroll
  for (int h = 0; h < 8; ++h)
#pragma unroll
    for (int r = 0; r < 4; ++r) {
      const int s = (t0w + g * 4 + r) & (S_ - 1);
      float p = accK[h][r] * Q[(size_t)s * E_ + h * 16 + c];
      p += __shfl_xor(p, 1, 64); p += __shfl_xor(p, 2, 64);
      p += __shfl_xor(p, 4, 64); p += __shfl_xor(p, 8, 64);
      w_arr[h][r] = __expf(p);
    }

#pragma unroll
  for (int nt = 0; nt < 8; ++nt)
#pragma unroll
    for (int r = 0; r < 4; ++r)
      num[(size_t)(t0w + g * 4 + r) * E_ + nt * 16 + c] = w_arr[nt][r] * accV[nt][r];

#pragma unroll
  for (int h = 0; h < 8; ++h)
    if (c == h) {
#pragma unroll
      for (int r = 0; r < 4; ++r)
        denom[(size_t)(t0w + g * 4 + r) * H_ + h] = w_arr[h][r];
    }
}

// ------------------------------------------------------------------
// K2: off-grid scatter. Bucketize, K/V MFMA, w=exp(q.k), atomic scatter.
// ------------------------------------------------------------------
__global__ __launch_bounds__(256, 2) void offgrid_mfma(
    const float* __restrict__ xc_off, const float* __restrict__ zc_off,
    const unsigned short* __restrict__ Wk_sw, const unsigned short* __restrict__ Wv_sw,
    const float* __restrict__ Q,
    float* __restrict__ num, float* __restrict__ denom) {
  __shared__ __align__(16) unsigned short wk[16384];
  __shared__ __align__(16) unsigned short wv[16384];
  const int tid = threadIdx.x;
  {
    const uint4* sk = (const uint4*)Wk_sw;
    const uint4* sv = (const uint4*)Wv_sw;
    uint4* dk = (uint4*)wk; uint4* dv = (uint4*)wv;
#pragma unroll
    for (int i = 0; i < 8; ++i) {
      dk[i * 256 + tid] = sk[i * 256 + tid];
      dv[i * 256 + tid] = sv[i * 256 + tid];
    }
  }

  const int wave = tid >> 6, lane = tid & 63;
  const int c = lane & 15, g = lane >> 4;
  const int t0w = blockIdx.x * 64 + wave * 16;   // token = b*U + u

  // bucketize: lane L computes seg for stripe-token (L&15); EXACT fp32 ref math
  int seg_self;
  {
    const int tok = t0w + c;
    const int b = tok >> 14;
    const float sp = 1.0f / 63.0f;
    const float half = sp * 0.5f;
    const float x0 = xc_off[(size_t)tok * 2 + 0];
    const float x1 = xc_off[(size_t)tok * 2 + 1];
    float n0 = floorf((x0 - 0.0f + half) / sp);
    float n1 = floorf((x1 - 0.0f + half) / sp);
    n0 = fminf(fmaxf(n0, 0.0f), 63.0f);
    n1 = fminf(fmaxf(n1, 0.0f), 63.0f);
    seg_self = b * S_ + (int)(n0 * 64.0f + n1);
  }
  int seg[4];
#pragma unroll
  for (int r = 0; r < 4; ++r) seg[r] = __shfl(seg_self, g * 4 + r, 64);

  __syncthreads();

  f32x4 accK[8], accV[8];
#pragma unroll
  for (int i = 0; i < 8; ++i) { accK[i] = {0.f,0.f,0.f,0.f}; accV[i] = {0.f,0.f,0.f,0.f}; }

  const float* arow = zc_off + (size_t)(t0w + c) * E_ + g * 8;
  const bf16x8* bk = (const bf16x8*)wk;
  const bf16x8* bv = (const bf16x8*)wv;
#pragma unroll
  for (int ks = 0; ks < 4; ++ks) {
    float4 a0 = *(const float4*)(arow + ks * 32);
    float4 a1 = *(const float4*)(arow + ks * 32 + 4);
    bf16x8 af = pack8(a0, a1);
    const int bo = (ks * 4 + g) * 128 + c;
#pragma unroll
    for (int nt = 0; nt < 8; ++nt) {
      accK[nt] = __builtin_amdgcn_mfma_f32_16x16x32_bf16(af, bk[bo + nt * 16], accK[nt], 0, 0, 0);
      accV[nt] = __builtin_amdgcn_mfma_f32_16x16x32_bf16(af, bv[bo + nt * 16], accV[nt], 0, 0, 0);
    }
  }

  float w_arr[8][4];
#pragma unroll
  for (int h = 0; h < 8; ++h)
#pragma unroll
    for (int r = 0; r < 4; ++r) {
      const int s = seg[r] & (S_ - 1);
      float p = accK[h][r] * Q[(size_t)s * E_ + h * 16 + c];
      p += __shfl_xor(p, 1, 64); p += __shfl_xor(p, 2, 64);
      p += __shfl_xor(p, 4, 64); p += __shfl_xor(p, 8, 64);
      w_arr[h][r] = __expf(p);
    }

#pragma unroll
  for (int nt = 0; nt < 8; ++nt)
#pragma unroll
    for (int r = 0; r < 4; ++r)
      atomicAdd(&num[(size_t)seg[r] * E_ + nt * 16 + c], w_arr[nt][r] * accV[nt][r]);

#pragma unroll
  for (int h = 0; h < 8; ++h)
    if (c == h) {
#pragma unroll
      for (int r = 0; r < 4; ++r)
        atomicAdd(&denom[(size_t)seg[r] * H_ + h], w_arr[h][r]);
    }
}

// ------------------------------------------------------------------
// K3: finalize in-place: out = (num/denom) @ Wo
// ------------------------------------------------------------------
__global__ __launch_bounds__(256, 4) void finalize_mfma(
    const unsigned short* __restrict__ Wo_sw, const float* __restrict__ denom,
    float* __restrict__ out) {
  __shared__ __align__(16) unsigned short wo[16384];
  const int tid = threadIdx.x;
  {
    const uint4* s = (const uint4*)Wo_sw;
    uint4* d = (uint4*)wo;
#pragma unroll
    for (int i = 0; i < 8; ++i) d[i * 256 + tid] = s[i * 256 + tid];
  }
  __syncthreads();

  const int wave = tid >> 6, lane = tid & 63;
  const int c = lane & 15, g = lane >> 4;
  const int t0w = blockIdx.x * 64 + wave * 16;

  f32x4 acc[8];
#pragma unroll
  for (int i = 0; i < 8; ++i) acc[i] = {0.f, 0.f, 0.f, 0.f};

  const float* nrow = out + (size_t)(t0w + c) * E_ + g * 8;
  const float* drow = denom + (size_t)(t0w + c) * H_;
  const bf16x8* bo_ = (const bf16x8*)wo;
#pragma unroll
  for (int ks = 0; ks < 4; ++ks) {
    const int head = (ks * 32 + g * 8) >> 4;
    const float dinv = 1.0f / drow[head];
    float4 a0 = *(const float4*)(nrow + ks * 32);
    float4 a1 = *(const float4*)(nrow + ks * 32 + 4);
    a0.x *= dinv; a0.y *= dinv; a0.z *= dinv; a0.w *= dinv;
    a1.x *= dinv; a1.y *= dinv; a1.z *= dinv; a1.w *= dinv;
    bf16x8 af = pack8(a0, a1);
    const int bofs = (ks * 4 + g) * 128 + c;
#pragma unroll
    for (int nt = 0; nt < 8; ++nt)
      acc[nt] = __builtin_amdgcn_mfma_f32_16x16x32_bf16(af, bo_[bofs + nt * 16], acc[nt], 0, 0, 0);
  }
#pragma unroll
  for (int nt = 0; nt < 8; ++nt)
#pragma unroll
    for (int r = 0; r < 4; ++r)
      out[(size_t)(t0w + g * 4 + r) * E_ + nt * 16 + c] = acc[nt][r];
}

// ------------------------------------------------------------------
extern "C" void kernel_launch(void* const* d_in, const int* in_sizes, int n_in,
                              void* d_out, int out_size, void* d_ws, size_t ws_size,
                              hipStream_t stream) {
  const float* xc_off  = (const float*)d_in[0];
  const float* zc_off  = (const float*)d_in[2];
  const float* zc_on   = (const float*)d_in[3];
  const float* latents = (const float*)d_in[4];
  const float* fake    = (const float*)d_in[5];
  const float* Wq      = (const float*)d_in[6];
  const float* Wk      = (const float*)d_in[7];
  const float* Wv      = (const float*)d_in[8];
  const float* Wo      = (const float*)d_in[9];
  const int*   ignore  = (const int*)d_in[10];

  float* out   = (float*)d_out;                        // doubles as num accumulator
  float* Q     = (float*)d_ws;                         // S*E fp32      (2 MB)
  float* denom = Q + (size_t)S_ * E_;                  // B*S*H fp32    (1 MB)
  unsigned short* Wsw = (unsigned short*)(denom + (size_t)B_ * S_ * H_);  // 4x32 KB bf16
  unsigned short* Wq_sw = Wsw;
  unsigned short* Wk_sw = Wsw + 16384;
  unsigned short* Wv_sw = Wsw + 32768;
  unsigned short* Wo_sw = Wsw + 49152;

  prep_weights<<<256, 256, 0, stream>>>(Wq, Wk, Wv, Wo, Wsw);
  qproj_mfma<<<S_ / 64, 256, 0, stream>>>(latents, Wq_sw, Q);
  ongrid_mfma<<<(B_ * S_) / 64, 256, 0, stream>>>(zc_on, fake, ignore, Wk_sw, Wv_sw, Q, out, denom);
  offgrid_mfma<<<(B_ * U_) / 64, 256, 0, stream>>>(xc_off, zc_off, Wk_sw, Wv_sw, Q, out, denom);
  finalize_mfma<<<(B_ * S_) / 64, 256, 0, stream>>>(Wo_sw, denom, out);
}

// Round 3
// 215.390 us; speedup vs baseline: 1.5515x; 1.0041x over previous
//
#include <hip/hip_runtime.h>
#include <math.h>

namespace {
constexpr int B_  = 8;
constexpr int U_  = 16384;
constexpr int S_  = 4096;
constexpr int E_  = 128;
constexpr int H_  = 8;
}

typedef __attribute__((ext_vector_type(8))) short bf16x8;
typedef __attribute__((ext_vector_type(4))) float f32x4;

__device__ inline unsigned short bf16rne(float x) {
  unsigned u = __float_as_uint(x);
  u = u + 0x7fffu + ((u >> 16) & 1u);
  return (unsigned short)(u >> 16);
}

__device__ inline bf16x8 pack8(float4 a, float4 b) {
  bf16x8 r;
  r[0] = (short)bf16rne(a.x); r[1] = (short)bf16rne(a.y);
  r[2] = (short)bf16rne(a.z); r[3] = (short)bf16rne(a.w);
  r[4] = (short)bf16rne(b.x); r[5] = (short)bf16rne(b.y);
  r[6] = (short)bf16rne(b.z); r[7] = (short)bf16rne(b.w);
  return r;
}

// ------------------------------------------------------------------
// P0: swizzle weights fp32 -> bf16 B-fragment layout.
// dst[w][ ((k>>3)*128 + n)*8 + (k&7) ] = bf16(W[k*128+n])
// ------------------------------------------------------------------
__global__ __launch_bounds__(256) void prep_weights(
    const float* __restrict__ Wq, const float* __restrict__ Wk,
    const float* __restrict__ Wv, const float* __restrict__ Wo,
    unsigned short* __restrict__ dst) {
  const int i = blockIdx.x * 256 + threadIdx.x;
  const int w = i >> 14, e = i & 16383;
  const int k = e >> 7, n = e & 127;
  const float* src = (w == 0) ? Wq : (w == 1) ? Wk : (w == 2) ? Wv : Wo;
  dst[w * 16384 + (((k >> 3) * 128 + n) << 3) + (k & 7)] = bf16rne(src[e]);
}

// ------------------------------------------------------------------
// K0: Qp = 0.25 * latents @ Wq, stored transposed-in-row: Qp[s][d*8+h]
// ------------------------------------------------------------------
__global__ __launch_bounds__(512, 4) void qproj_mfma(
    const float* __restrict__ latents, const unsigned short* __restrict__ Wq_sw,
    float* __restrict__ Qp) {
  __shared__ __align__(16) unsigned short wq[16384];
  const int tid = threadIdx.x;
  {
    const uint4* s = (const uint4*)Wq_sw;
    uint4* d = (uint4*)wq;
#pragma unroll
    for (int i = 0; i < 4; ++i) d[i * 512 + tid] = s[i * 512 + tid];
  }
  __syncthreads();

  const int wave = tid >> 6, lane = tid & 63;
  const int c = lane & 15, g = lane >> 4;
  const int t0w = blockIdx.x * 128 + wave * 16;

  f32x4 acc[8];
#pragma unroll
  for (int i = 0; i < 8; ++i) acc[i] = {0.f, 0.f, 0.f, 0.f};

  const float* arow = latents + (size_t)(t0w + c) * E_ + g * 8;
  const bf16x8* bq = (const bf16x8*)wq;
#pragma unroll
  for (int ks = 0; ks < 4; ++ks) {
    float4 a0 = *(const float4*)(arow + ks * 32);
    float4 a1 = *(const float4*)(arow + ks * 32 + 4);
    bf16x8 af = pack8(a0, a1);
    const int bo = (ks * 4 + g) * 128 + c;
#pragma unroll
    for (int nt = 0; nt < 8; ++nt)
      acc[nt] = __builtin_amdgcn_mfma_f32_16x16x32_bf16(af, bq[bo + nt * 16], acc[nt], 0, 0, 0);
  }
  // element (token=t0w+g*4+r, head=nt, d=c) -> Qp[token][c*8+nt]
#pragma unroll
  for (int nt = 0; nt < 8; ++nt)
#pragma unroll
    for (int r = 0; r < 4; ++r)
      Qp[(size_t)(t0w + g * 4 + r) * E_ + c * 8 + nt] = acc[nt][r] * 0.25f;
}

// ------------------------------------------------------------------
// K1: on-grid init.  K=z@Wk, V=z@Wv, w=exp(q.k);
// denom[tok][h]=w ; num[tok][n]=w*V  (direct stores)
// ------------------------------------------------------------------
__global__ __launch_bounds__(512, 4) void ongrid_mfma(
    const float* __restrict__ zc_on, const float* __restrict__ fake,
    const int* __restrict__ ignore_flag,
    const unsigned short* __restrict__ Wk_sw, const unsigned short* __restrict__ Wv_sw,
    const float* __restrict__ Qp,
    float* __restrict__ num, float* __restrict__ denom) {
  __shared__ __align__(16) unsigned short wk[16384];
  __shared__ __align__(16) unsigned short wv[16384];
  const int tid = threadIdx.x;
  {
    const uint4* sk = (const uint4*)Wk_sw;
    const uint4* sv = (const uint4*)Wv_sw;
    uint4* dk = (uint4*)wk; uint4* dv = (uint4*)wv;
#pragma unroll
    for (int i = 0; i < 4; ++i) {
      dk[i * 512 + tid] = sk[i * 512 + tid];
      dv[i * 512 + tid] = sv[i * 512 + tid];
    }
  }
  const int ign = *ignore_flag;
  __syncthreads();

  const int wave = tid >> 6, lane = tid & 63;
  const int c = lane & 15, g = lane >> 4;
  const int t0w = blockIdx.x * 128 + wave * 16;   // token = b*S + s

  // prefetch Q rows (rows are cells s = token & (S-1))
  float4 qa[4], qb[4];
#pragma unroll
  for (int r = 0; r < 4; ++r) {
    const int s = (t0w + g * 4 + r) & (S_ - 1);
    qa[r] = *(const float4*)(Qp + (size_t)s * E_ + c * 8);
    qb[r] = *(const float4*)(Qp + (size_t)s * E_ + c * 8 + 4);
  }

  f32x4 accK[8], accV[8];
#pragma unroll
  for (int i = 0; i < 8; ++i) { accK[i] = {0.f,0.f,0.f,0.f}; accV[i] = {0.f,0.f,0.f,0.f}; }

  const float* arow = ign ? (fake + g * 8)
                          : (zc_on + (size_t)(t0w + c) * E_ + g * 8);
  const bf16x8* bk = (const bf16x8*)wk;
  const bf16x8* bv = (const bf16x8*)wv;
#pragma unroll
  for (int ks = 0; ks < 4; ++ks) {
    float4 a0 = *(const float4*)(arow + ks * 32);
    float4 a1 = *(const float4*)(arow + ks * 32 + 4);
    bf16x8 af = pack8(a0, a1);
    const int bo = (ks * 4 + g) * 128 + c;
#pragma unroll
    for (int nt = 0; nt < 8; ++nt) {
      accK[nt] = __builtin_amdgcn_mfma_f32_16x16x32_bf16(af, bk[bo + nt * 16], accK[nt], 0, 0, 0);
      accV[nt] = __builtin_amdgcn_mfma_f32_16x16x32_bf16(af, bv[bo + nt * 16], accV[nt], 0, 0, 0);
    }
  }

  float w_arr[8][4];
#pragma unroll
  for (int h = 0; h < 8; ++h)
#pragma unroll
    for (int r = 0; r < 4; ++r) {
      const float qv = (h < 4) ? qa[r][h] : qb[r][h - 4];
      float p = accK[h][r] * qv;
      p += __shfl_xor(p, 1, 64); p += __shfl_xor(p, 2, 64);
      p += __shfl_xor(p, 4, 64); p += __shfl_xor(p, 8, 64);
      w_arr[h][r] = __expf(p);
    }

#pragma unroll
  for (int nt = 0; nt < 8; ++nt)
#pragma unroll
    for (int r = 0; r < 4; ++r)
      num[(size_t)(t0w + g * 4 + r) * E_ + nt * 16 + c] = w_arr[nt][r] * accV[nt][r];

#pragma unroll
  for (int h = 0; h < 8; ++h)
    if (c == h) {
#pragma unroll
      for (int r = 0; r < 4; ++r)
        denom[(size_t)(t0w + g * 4 + r) * H_ + h] = w_arr[h][r];
    }
}

// ------------------------------------------------------------------
// K2: off-grid scatter. Bucketize, K/V MFMA, w=exp(q.k), atomic scatter.
// ------------------------------------------------------------------
__global__ __launch_bounds__(512, 4) void offgrid_mfma(
    const float* __restrict__ xc_off, const float* __restrict__ zc_off,
    const unsigned short* __restrict__ Wk_sw, const unsigned short* __restrict__ Wv_sw,
    const float* __restrict__ Qp,
    float* __restrict__ num, float* __restrict__ denom) {
  __shared__ __align__(16) unsigned short wk[16384];
  __shared__ __align__(16) unsigned short wv[16384];
  const int tid = threadIdx.x;
  {
    const uint4* sk = (const uint4*)Wk_sw;
    const uint4* sv = (const uint4*)Wv_sw;
    uint4* dk = (uint4*)wk; uint4* dv = (uint4*)wv;
#pragma unroll
    for (int i = 0; i < 4; ++i) {
      dk[i * 512 + tid] = sk[i * 512 + tid];
      dv[i * 512 + tid] = sv[i * 512 + tid];
    }
  }

  const int wave = tid >> 6, lane = tid & 63;
  const int c = lane & 15, g = lane >> 4;
  const int t0w = blockIdx.x * 128 + wave * 16;   // token = b*U + u

  // bucketize (EXACT fp32 ref math); lane c holds seg of token t0w+c
  int seg_self;
  {
    const int tok = t0w + c;
    const int b = tok >> 14;
    const float sp = 1.0f / 63.0f;
    const float half = sp * 0.5f;
    const float x0 = xc_off[(size_t)tok * 2 + 0];
    const float x1 = xc_off[(size_t)tok * 2 + 1];
    float n0 = floorf((x0 - 0.0f + half) / sp);
    float n1 = floorf((x1 - 0.0f + half) / sp);
    n0 = fminf(fmaxf(n0, 0.0f), 63.0f);
    n1 = fminf(fmaxf(n1, 0.0f), 63.0f);
    seg_self = b * S_ + (int)(n0 * 64.0f + n1);
  }
  int seg[4];
#pragma unroll
  for (int r = 0; r < 4; ++r) seg[r] = __shfl(seg_self, g * 4 + r, 64);

  __syncthreads();

  // prefetch Q rows for this wave's 16 tokens
  float4 qa[4], qb[4];
#pragma unroll
  for (int r = 0; r < 4; ++r) {
    const int s = seg[r] & (S_ - 1);
    qa[r] = *(const float4*)(Qp + (size_t)s * E_ + c * 8);
    qb[r] = *(const float4*)(Qp + (size_t)s * E_ + c * 8 + 4);
  }

  f32x4 accK[8], accV[8];
#pragma unroll
  for (int i = 0; i < 8; ++i) { accK[i] = {0.f,0.f,0.f,0.f}; accV[i] = {0.f,0.f,0.f,0.f}; }

  const float* arow = zc_off + (size_t)(t0w + c) * E_ + g * 8;
  const bf16x8* bk = (const bf16x8*)wk;
  const bf16x8* bv = (const bf16x8*)wv;
#pragma unroll
  for (int ks = 0; ks < 4; ++ks) {
    float4 a0 = *(const float4*)(arow + ks * 32);
    float4 a1 = *(const float4*)(arow + ks * 32 + 4);
    bf16x8 af = pack8(a0, a1);
    const int bo = (ks * 4 + g) * 128 + c;
#pragma unroll
    for (int nt = 0; nt < 8; ++nt) {
      accK[nt] = __builtin_amdgcn_mfma_f32_16x16x32_bf16(af, bk[bo + nt * 16], accK[nt], 0, 0, 0);
      accV[nt] = __builtin_amdgcn_mfma_f32_16x16x32_bf16(af, bv[bo + nt * 16], accV[nt], 0, 0, 0);
    }
  }

  float w_arr[8][4];
#pragma unroll
  for (int h = 0; h < 8; ++h)
#pragma unroll
    for (int r = 0; r < 4; ++r) {
      const float qv = (h < 4) ? qa[r][h] : qb[r][h - 4];
      float p = accK[h][r] * qv;
      p += __shfl_xor(p, 1, 64); p += __shfl_xor(p, 2, 64);
      p += __shfl_xor(p, 4, 64); p += __shfl_xor(p, 8, 64);
      w_arr[h][r] = __expf(p);
    }

#pragma unroll
  for (int nt = 0; nt < 8; ++nt)
#pragma unroll
    for (int r = 0; r < 4; ++r)
      atomicAdd(&num[(size_t)seg[r] * E_ + nt * 16 + c], w_arr[nt][r] * accV[nt][r]);

#pragma unroll
  for (int h = 0; h < 8; ++h)
    if (c == h) {
#pragma unroll
      for (int r = 0; r < 4; ++r)
        atomicAdd(&denom[(size_t)seg[r] * H_ + h], w_arr[h][r]);
    }
}

// ------------------------------------------------------------------
// K3: finalize in-place: out = (num/denom) @ Wo
// ------------------------------------------------------------------
__global__ __launch_bounds__(512, 4) void finalize_mfma(
    const unsigned short* __restrict__ Wo_sw, const float* __restrict__ denom,
    float* __restrict__ out) {
  __shared__ __align__(16) unsigned short wo[16384];
  const int tid = threadIdx.x;
  {
    const uint4* s = (const uint4*)Wo_sw;
    uint4* d = (uint4*)wo;
#pragma unroll
    for (int i = 0; i < 4; ++i) d[i * 512 + tid] = s[i * 512 + tid];
  }
  __syncthreads();

  const int wave = tid >> 6, lane = tid & 63;
  const int c = lane & 15, g = lane >> 4;
  const int t0w = blockIdx.x * 128 + wave * 16;

  f32x4 acc[8];
#pragma unroll
  for (int i = 0; i < 8; ++i) acc[i] = {0.f, 0.f, 0.f, 0.f};

  const float* nrow = out + (size_t)(t0w + c) * E_ + g * 8;
  const float* drow = denom + (size_t)(t0w + c) * H_;
  const bf16x8* bo_ = (const bf16x8*)wo;
#pragma unroll
  for (int ks = 0; ks < 4; ++ks) {
    const int head = (ks * 32 + g * 8) >> 4;
    const float dinv = 1.0f / drow[head];
    float4 a0 = *(const float4*)(nrow + ks * 32);
    float4 a1 = *(const float4*)(nrow + ks * 32 + 4);
    a0.x *= dinv; a0.y *= dinv; a0.z *= dinv; a0.w *= dinv;
    a1.x *= dinv; a1.y *= dinv; a1.z *= dinv; a1.w *= dinv;
    bf16x8 af = pack8(a0, a1);
    const int bofs = (ks * 4 + g) * 128 + c;
#pragma unroll
    for (int nt = 0; nt < 8; ++nt)
      acc[nt] = __builtin_amdgcn_mfma_f32_16x16x32_bf16(af, bo_[bofs + nt * 16], acc[nt], 0, 0, 0);
  }
#pragma unroll
  for (int nt = 0; nt < 8; ++nt)
#pragma unroll
    for (int r = 0; r < 4; ++r)
      out[(size_t)(t0w + g * 4 + r) * E_ + nt * 16 + c] = acc[nt][r];
}

// ------------------------------------------------------------------
extern "C" void kernel_launch(void* const* d_in, const int* in_sizes, int n_in,
                              void* d_out, int out_size, void* d_ws, size_t ws_size,
                              hipStream_t stream) {
  const float* xc_off  = (const float*)d_in[0];
  const float* zc_off  = (const float*)d_in[2];
  const float* zc_on   = (const float*)d_in[3];
  const float* latents = (const float*)d_in[4];
  const float* fake    = (const float*)d_in[5];
  const float* Wq      = (const float*)d_in[6];
  const float* Wk      = (const float*)d_in[7];
  const float* Wv      = (const float*)d_in[8];
  const float* Wo      = (const float*)d_in[9];
  const int*   ignore  = (const int*)d_in[10];

  float* out   = (float*)d_out;                        // doubles as num accumulator
  float* Qp    = (float*)d_ws;                         // S*E fp32      (2 MB)
  float* denom = Qp + (size_t)S_ * E_;                 // B*S*H fp32    (1 MB)
  unsigned short* Wsw = (unsigned short*)(denom + (size_t)B_ * S_ * H_);
  unsigned short* Wq_sw = Wsw;
  unsigned short* Wk_sw = Wsw + 16384;
  unsigned short* Wv_sw = Wsw + 32768;
  unsigned short* Wo_sw = Wsw + 49152;

  prep_weights<<<256, 256, 0, stream>>>(Wq, Wk, Wv, Wo, Wsw);
  qproj_mfma<<<S_ / 128, 512, 0, stream>>>(latents, Wq_sw, Qp);
  ongrid_mfma<<<(B_ * S_) / 128, 512, 0, stream>>>(zc_on, fake, ignore, Wk_sw, Wv_sw, Qp, out, denom);
  offgrid_mfma<<<(B_ * U_) / 128, 512, 0, stream>>>(xc_off, zc_off, Wk_sw, Wv_sw, Qp, out, denom);
  finalize_mfma<<<(B_ * S_) / 128, 512, 0, stream>>>(Wo_sw, denom, out);
}